// Round 4
// baseline (48.350 us; speedup 1.0000x reference)
//
#include <hip/hip_runtime.h>
#include <math.h>

// Input:  x (16, 31, 256, 256) float32
// Output: sqrt(v^2 + h^2 + 1e-6), v = x[y+1]-x[y-1], h = x[:,x+1]-x[:,x-1],
// zero padding at the borders.
//
// R4: same strip structure as R3 (STRIP=16, 128-thd blocks, XCD swizzle) but
// (a) REGULAR stores instead of nontemporal: input (124 MiB) + output
//     (124 MiB) = 248 MiB fits the 256 MiB memory-side Infinity Cache, so in
//     steady-state graph replay the output lines are overwritten in-cache and
//     HBM write traffic collapses;
// (b) sched_barrier(0) after the load batch pins all 18 row-loads in flight
//     (compiler was interleaving them into the compute, VGPR=36 -> shallow MLP).

#define IMG_H 256
#define IMG_W 256
#define EPS   1e-6f
#define STRIP 16                   // output rows per wave/lane
#define WAVES_PER_BLOCK 2
#define ROWS_PER_BLOCK (STRIP * WAVES_PER_BLOCK)   // 32
#define BANDS (IMG_H / ROWS_PER_BLOCK)             // 8

typedef float f32x4 __attribute__((ext_vector_type(4)));

__global__ __launch_bounds__(128) void grad_mag_kernel(
    const float* __restrict__ in, float* __restrict__ out)
{
    const int tid  = threadIdx.x;
    const int lane = tid & 63;
    const int wv   = tid >> 6;                    // wave within block: 0..1

    // XCD-chunked swizzle (bijective: gridDim.x = 3968 divisible by 8).
    const int chunk = gridDim.x >> 3;
    const int sid   = (blockIdx.x & 7) * chunk + (blockIdx.x >> 3);

    const int band        = sid & (BANDS - 1);
    const long long plane = sid >> 3;             // 0..495

    const int y0 = band * ROWS_PER_BLOCK + wv * STRIP;  // first output row
    const int x0 = lane * 4;

    const float* __restrict__ p = in  + plane * (long long)(IMG_H * IMG_W) + x0;
    float*       __restrict__ q = out + plane * (long long)(IMG_H * IMG_W) + x0;

    // Load rows y0-1 .. y0+STRIP unconditionally from clamped addresses
    // (branch-free, back-to-back issue -> 18 outstanding loads per lane).
    f32x4 r[STRIP + 2];
    #pragma unroll
    for (int i = 0; i < STRIP + 2; ++i) {
        const int y  = y0 - 1 + i;
        const int yc = y < 0 ? 0 : (y > IMG_H - 1 ? IMG_H - 1 : y);
        r[i] = *reinterpret_cast<const f32x4*>(p + (long long)yc * IMG_W);
    }
    // Keep the load batch together — do not let compute interleave upward.
    __builtin_amdgcn_sched_barrier(0);

    #pragma unroll
    for (int i = 0; i < STRIP + 2; ++i) {
        const int y = y0 - 1 + i;
        if (y < 0 || y > IMG_H - 1) r[i] = (f32x4)0.f;
    }

    #pragma unroll
    for (int i = 0; i < STRIP; ++i) {
        const f32x4 up  = r[i];
        const f32x4 cur = r[i + 1];
        const f32x4 dn  = r[i + 2];

        // Horizontal neighbors across lanes (wave spans exactly one row).
        float left  = __shfl_up(cur.w, 1);
        float right = __shfl_down(cur.x, 1);
        if (lane == 0)  left  = 0.f;     // zero pad at x = -1
        if (lane == 63) right = 0.f;     // zero pad at x = 256

        f32x4 h, v, o;
        h.x = cur.y - left;
        h.y = cur.z - cur.x;
        h.z = cur.w - cur.y;
        h.w = right - cur.z;
        v = dn - up;

        o.x = __builtin_amdgcn_sqrtf(v.x * v.x + h.x * h.x + EPS);
        o.y = __builtin_amdgcn_sqrtf(v.y * v.y + h.y * h.y + EPS);
        o.z = __builtin_amdgcn_sqrtf(v.z * v.z + h.z * h.z + EPS);
        o.w = __builtin_amdgcn_sqrtf(v.w * v.w + h.w * h.w + EPS);

        *reinterpret_cast<f32x4*>(q + (long long)(y0 + i) * IMG_W) = o;
    }
}

extern "C" void kernel_launch(void* const* d_in, const int* in_sizes, int n_in,
                              void* d_out, int out_size, void* d_ws, size_t ws_size,
                              hipStream_t stream)
{
    const float* x = (const float*)d_in[0];
    float* out = (float*)d_out;

    const int planes = in_sizes[0] / (IMG_H * IMG_W);        // 16*31 = 496
    const int grid   = planes * BANDS;                       // 496 * 8 = 3968

    grad_mag_kernel<<<grid, 128, 0, stream>>>(x, out);
}

// Round 5
// 42.312 us; speedup vs baseline: 1.1427x; 1.1427x over previous
//
#include <hip/hip_runtime.h>
#include <math.h>

// Input:  x (16, 31, 256, 256) float32
// Output: sqrt(v^2 + h^2 + 1e-6), v = x[y+1]-x[y-1], h = x[:,x+1]-x[:,x-1],
// zero padding at the borders.
//
// R5: R3 structure (STRIP=16, 128-thd blocks, XCD swizzle, NONTEMPORAL
// stores — R4 proved regular stores thrash L3 and regress) plus
// sched_barrier(0) after the load batch so all 18 row-loads stay in flight
// (R3's VGPR=36 showed the compiler interleaving loads into compute ->
// shallow MLP, VALUBusy 9.5%).

#define IMG_H 256
#define IMG_W 256
#define EPS   1e-6f
#define STRIP 16                   // output rows per wave/lane
#define WAVES_PER_BLOCK 2
#define ROWS_PER_BLOCK (STRIP * WAVES_PER_BLOCK)   // 32
#define BANDS (IMG_H / ROWS_PER_BLOCK)             // 8

typedef float f32x4 __attribute__((ext_vector_type(4)));

__global__ __launch_bounds__(128) void grad_mag_kernel(
    const float* __restrict__ in, float* __restrict__ out)
{
    const int tid  = threadIdx.x;
    const int lane = tid & 63;
    const int wv   = tid >> 6;                    // wave within block: 0..1

    // XCD-chunked swizzle (bijective: gridDim.x = 3968 divisible by 8).
    const int chunk = gridDim.x >> 3;
    const int sid   = (blockIdx.x & 7) * chunk + (blockIdx.x >> 3);

    const int band        = sid & (BANDS - 1);
    const long long plane = sid >> 3;             // 0..495

    const int y0 = band * ROWS_PER_BLOCK + wv * STRIP;  // first output row
    const int x0 = lane * 4;

    const float* __restrict__ p = in  + plane * (long long)(IMG_H * IMG_W) + x0;
    float*       __restrict__ q = out + plane * (long long)(IMG_H * IMG_W) + x0;

    // Load rows y0-1 .. y0+STRIP unconditionally from clamped addresses
    // (branch-free, back-to-back issue -> 18 outstanding loads per lane).
    f32x4 r[STRIP + 2];
    #pragma unroll
    for (int i = 0; i < STRIP + 2; ++i) {
        const int y  = y0 - 1 + i;
        const int yc = y < 0 ? 0 : (y > IMG_H - 1 ? IMG_H - 1 : y);
        r[i] = *reinterpret_cast<const f32x4*>(p + (long long)yc * IMG_W);
    }
    // Keep the load batch together — do not let compute interleave upward.
    __builtin_amdgcn_sched_barrier(0);

    #pragma unroll
    for (int i = 0; i < STRIP + 2; ++i) {
        const int y = y0 - 1 + i;
        if (y < 0 || y > IMG_H - 1) r[i] = (f32x4)0.f;
    }

    #pragma unroll
    for (int i = 0; i < STRIP; ++i) {
        const f32x4 up  = r[i];
        const f32x4 cur = r[i + 1];
        const f32x4 dn  = r[i + 2];

        // Horizontal neighbors across lanes (wave spans exactly one row).
        float left  = __shfl_up(cur.w, 1);
        float right = __shfl_down(cur.x, 1);
        if (lane == 0)  left  = 0.f;     // zero pad at x = -1
        if (lane == 63) right = 0.f;     // zero pad at x = 256

        f32x4 h, v, o;
        h.x = cur.y - left;
        h.y = cur.z - cur.x;
        h.z = cur.w - cur.y;
        h.w = right - cur.z;
        v = dn - up;

        o.x = __builtin_amdgcn_sqrtf(v.x * v.x + h.x * h.x + EPS);
        o.y = __builtin_amdgcn_sqrtf(v.y * v.y + h.y * h.y + EPS);
        o.z = __builtin_amdgcn_sqrtf(v.z * v.z + h.z * h.z + EPS);
        o.w = __builtin_amdgcn_sqrtf(v.w * v.w + h.w * h.w + EPS);

        __builtin_nontemporal_store(
            o, reinterpret_cast<f32x4*>(q + (long long)(y0 + i) * IMG_W));
    }
}

extern "C" void kernel_launch(void* const* d_in, const int* in_sizes, int n_in,
                              void* d_out, int out_size, void* d_ws, size_t ws_size,
                              hipStream_t stream)
{
    const float* x = (const float*)d_in[0];
    float* out = (float*)d_out;

    const int planes = in_sizes[0] / (IMG_H * IMG_W);        // 16*31 = 496
    const int grid   = planes * BANDS;                       // 496 * 8 = 3968

    grad_mag_kernel<<<grid, 128, 0, stream>>>(x, out);
}

// Round 6
// 40.854 us; speedup vs baseline: 1.1835x; 1.0357x over previous
//
#include <hip/hip_runtime.h>
#include <math.h>

// Input:  x (16, 31, 256, 256) float32
// Output: sqrt(v^2 + h^2 + 1e-6), v = x[y+1]-x[y-1], h = x[:,x+1]-x[:,x-1],
// zero padding at the borders.
//
// R6: generation-staggering experiment. STRIP=8 with 256-thread blocks doubles
// the wave count (15,872 waves = 2 generations per CU) so gen-2 reads overlap
// gen-1 writes machine-wide (R5's single generation phase-separated the read
// and write bursts; occupancy 34%, BW stuck at 4.6 TB/s). Keeps R5's proven
// pieces: XCD-chunked swizzle, sched_barrier load batch, NT stores, v_sqrt.

#define IMG_H 256
#define IMG_W 256
#define EPS   1e-6f
#define STRIP 8                    // output rows per wave/lane
#define WAVES_PER_BLOCK 4
#define ROWS_PER_BLOCK (STRIP * WAVES_PER_BLOCK)   // 32
#define BANDS (IMG_H / ROWS_PER_BLOCK)             // 8

typedef float f32x4 __attribute__((ext_vector_type(4)));

__global__ __launch_bounds__(256) void grad_mag_kernel(
    const float* __restrict__ in, float* __restrict__ out)
{
    const int tid  = threadIdx.x;
    const int lane = tid & 63;
    const int wv   = tid >> 6;                    // wave within block: 0..3

    // XCD-chunked swizzle (bijective: gridDim.x = 3968 divisible by 8).
    const int chunk = gridDim.x >> 3;
    const int sid   = (blockIdx.x & 7) * chunk + (blockIdx.x >> 3);

    const int band        = sid & (BANDS - 1);
    const long long plane = sid >> 3;             // 0..495

    const int y0 = band * ROWS_PER_BLOCK + wv * STRIP;  // first output row
    const int x0 = lane * 4;

    const float* __restrict__ p = in  + plane * (long long)(IMG_H * IMG_W) + x0;
    float*       __restrict__ q = out + plane * (long long)(IMG_H * IMG_W) + x0;

    // Load rows y0-1 .. y0+STRIP unconditionally from clamped addresses
    // (branch-free, back-to-back issue -> 10 outstanding loads per lane).
    f32x4 r[STRIP + 2];
    #pragma unroll
    for (int i = 0; i < STRIP + 2; ++i) {
        const int y  = y0 - 1 + i;
        const int yc = y < 0 ? 0 : (y > IMG_H - 1 ? IMG_H - 1 : y);
        r[i] = *reinterpret_cast<const f32x4*>(p + (long long)yc * IMG_W);
    }
    // Keep the load batch together — do not let compute interleave upward.
    __builtin_amdgcn_sched_barrier(0);

    #pragma unroll
    for (int i = 0; i < STRIP + 2; ++i) {
        const int y = y0 - 1 + i;
        if (y < 0 || y > IMG_H - 1) r[i] = (f32x4)0.f;
    }

    #pragma unroll
    for (int i = 0; i < STRIP; ++i) {
        const f32x4 up  = r[i];
        const f32x4 cur = r[i + 1];
        const f32x4 dn  = r[i + 2];

        // Horizontal neighbors across lanes (wave spans exactly one row).
        float left  = __shfl_up(cur.w, 1);
        float right = __shfl_down(cur.x, 1);
        if (lane == 0)  left  = 0.f;     // zero pad at x = -1
        if (lane == 63) right = 0.f;     // zero pad at x = 256

        f32x4 h, v, o;
        h.x = cur.y - left;
        h.y = cur.z - cur.x;
        h.z = cur.w - cur.y;
        h.w = right - cur.z;
        v = dn - up;

        o.x = __builtin_amdgcn_sqrtf(v.x * v.x + h.x * h.x + EPS);
        o.y = __builtin_amdgcn_sqrtf(v.y * v.y + h.y * h.y + EPS);
        o.z = __builtin_amdgcn_sqrtf(v.z * v.z + h.z * h.z + EPS);
        o.w = __builtin_amdgcn_sqrtf(v.w * v.w + h.w * h.w + EPS);

        __builtin_nontemporal_store(
            o, reinterpret_cast<f32x4*>(q + (long long)(y0 + i) * IMG_W));
    }
}

extern "C" void kernel_launch(void* const* d_in, const int* in_sizes, int n_in,
                              void* d_out, int out_size, void* d_ws, size_t ws_size,
                              hipStream_t stream)
{
    const float* x = (const float*)d_in[0];
    float* out = (float*)d_out;

    const int planes = in_sizes[0] / (IMG_H * IMG_W);        // 16*31 = 496
    const int grid   = planes * BANDS;                       // 496 * 8 = 3968

    grad_mag_kernel<<<grid, 256, 0, stream>>>(x, out);
}